// Round 1
// baseline (1663.016 us; speedup 1.0000x reference)
//
#include <hip/hip_runtime.h>
#include <hip/hip_bf16.h>

// Problem constants (match reference)
#define NN   6
#define CC   80
#define DD   118
#define HH   32
#define WW   88
#define DHW  (DD * HH * WW)          // 332288
#define MM   1036800
#define BH   360
#define BW   360
#define KK   (BH * BW)               // 129600

// Kernel 1: per-point precompute. pw[p] = { n*C*DHW + rem, bits(depth_weights[idx]) }
__global__ __launch_bounds__(256) void bev_prep(const int* __restrict__ indices,
                                                const float* __restrict__ dw,
                                                int2* __restrict__ pw) {
    int p = blockIdx.x * 256 + threadIdx.x;
    if (p >= MM) return;
    int i = indices[p];
    unsigned ui = (unsigned)i;
    unsigned n = ui / (unsigned)DHW;          // constant divisor -> magic mul
    unsigned rem = ui - n * (unsigned)DHW;
    float w = dw[i];
    pw[p] = make_int2((int)(n * (unsigned)(CC * DHW) + rem), __float_as_int(w));
}

// Kernel 2: one thread per (c, k). k fastest -> coalesced interval loads,
// coalesced output stores, and slow c sweep keeps the gather working set
// (a few (n,:,c) planes, ~8 MB each) L2/L3 resident.
__global__ __launch_bounds__(256) void bev_pool(const float* __restrict__ cf,
                                                const int2* __restrict__ pw,
                                                const int* __restrict__ intervals,
                                                float* __restrict__ out) {
    int t = blockIdx.x * 256 + threadIdx.x;
    if (t >= CC * KK) return;
    int k = t % KK;                            // constant divisor -> magic mul
    int c = t / KK;
    int s = intervals[3 * k];
    int e = intervals[3 * k + 1];
    int b = intervals[3 * k + 2];
    const float* __restrict__ cfc = cf + (size_t)c * DHW;
    float acc = 0.f;
    int len = e - s;
    if (len == 8) {
        // fast path: 8 independent loads in flight
        int2 v0 = pw[s + 0]; int2 v1 = pw[s + 1]; int2 v2 = pw[s + 2]; int2 v3 = pw[s + 3];
        int2 v4 = pw[s + 4]; int2 v5 = pw[s + 5]; int2 v6 = pw[s + 6]; int2 v7 = pw[s + 7];
        float f0 = cfc[v0.x], f1 = cfc[v1.x], f2 = cfc[v2.x], f3 = cfc[v3.x];
        float f4 = cfc[v4.x], f5 = cfc[v5.x], f6 = cfc[v6.x], f7 = cfc[v7.x];
        acc = __int_as_float(v0.y) * f0 + __int_as_float(v1.y) * f1
            + __int_as_float(v2.y) * f2 + __int_as_float(v3.y) * f3
            + __int_as_float(v4.y) * f4 + __int_as_float(v5.y) * f5
            + __int_as_float(v6.y) * f6 + __int_as_float(v7.y) * f7;
    } else {
        for (int p = s; p < e; ++p) {
            int2 v = pw[p];
            acc += __int_as_float(v.y) * cfc[v.x];
        }
    }
    out[(size_t)c * KK + b] = acc;
}

// Fallback (no workspace): inline per-point recompute.
__global__ __launch_bounds__(256) void bev_pool_inline(const float* __restrict__ cf,
                                                       const float* __restrict__ dw,
                                                       const int* __restrict__ indices,
                                                       const int* __restrict__ intervals,
                                                       float* __restrict__ out) {
    int t = blockIdx.x * 256 + threadIdx.x;
    if (t >= CC * KK) return;
    int k = t % KK;
    int c = t / KK;
    int s = intervals[3 * k];
    int e = intervals[3 * k + 1];
    int b = intervals[3 * k + 2];
    const float* __restrict__ cfc = cf + (size_t)c * DHW;
    float acc = 0.f;
    for (int p = s; p < e; ++p) {
        int i = indices[p];
        unsigned ui = (unsigned)i;
        unsigned n = ui / (unsigned)DHW;
        unsigned rem = ui - n * (unsigned)DHW;
        acc += dw[i] * cfc[n * (unsigned)(CC * DHW) + rem];
    }
    out[(size_t)c * KK + b] = acc;
}

extern "C" void kernel_launch(void* const* d_in, const int* in_sizes, int n_in,
                              void* d_out, int out_size, void* d_ws, size_t ws_size,
                              hipStream_t stream) {
    const float* cf        = (const float*)d_in[0];
    const float* dw        = (const float*)d_in[1];
    const int*   indices   = (const int*)d_in[2];
    const int*   intervals = (const int*)d_in[3];
    float* out = (float*)d_out;

    const int total = CC * KK;
    const int poolBlocks = (total + 255) / 256;

    if (ws_size >= (size_t)MM * sizeof(int2)) {
        int2* pw = (int2*)d_ws;
        bev_prep<<<(MM + 255) / 256, 256, 0, stream>>>(indices, dw, pw);
        bev_pool<<<poolBlocks, 256, 0, stream>>>(cf, pw, intervals, out);
    } else {
        bev_pool_inline<<<poolBlocks, 256, 0, stream>>>(cf, dw, indices, intervals, out);
    }
}